// Round 1
// 294.711 us; speedup vs baseline: 1.1850x; 1.1850x over previous
//
#include <hip/hip_runtime.h>
#include <math.h>

// Problem constants (fixed by the reference)
#define BATCH 65536
#define DIM 128
#define NBAS 6
#define OUTW 896              // DIM*NBAS + DIM
#define ROWS_PER_TILE 64
#define LDS_STRIDE 68         // pad: 16B-aligned b128 reads, breaks pow2 store conflicts

// ---------------------------------------------------------------------------
// Kernel 1: S = sigmoid(W), 128x128 into workspace. Trivial.
// ---------------------------------------------------------------------------
__global__ __launch_bounds__(256) void sigmoid_k(const float* __restrict__ W,
                                                 float* __restrict__ S) {
    int t = blockIdx.x * 256 + threadIdx.x;
    float w = W[t];
    S[t] = 1.0f / (1.0f + expf(-w));
}

// ---------------------------------------------------------------------------
// Closed-form uniform cubic B-spline weights.
// Knots = linspace(-1,1,10), h = 2/9. For x with p=(x+1)*4.5, s=floor(p),
// u=p-s: the only nonzero basis entries are t = s-3..s with
//   B[s]   = u^3/6
//   B[s-1] = (-3u^3+3u^2+3u+1)/6
//   B[s-2] = (3u^3-6u^2+4)/6
//   B[s-3] = (1-u)^3/6
// (identical to the Cox-de Boor ladder for this uniform non-clamped vector;
//  entries outside [0,5] are truncated exactly as the reference truncates.)
// ---------------------------------------------------------------------------
__device__ __forceinline__ void bw(float x, int& s,
                                   float& w0, float& w1, float& w2, float& w3) {
    const float i6 = 0.16666666666666666f;
    float xc = fminf(fmaxf(x, -1.0f), 1.0f - 1e-6f);
    float p  = (xc + 1.0f) * 4.5f;
    float sf = floorf(p);
    float u  = p - sf;
    s = (int)sf;                       // 0..8
    float u2 = u * u;
    float v  = 1.0f - u;
    w0 = u * u2 * i6;                                      // d = 0  (t = s)
    w1 = (((-3.0f * u + 3.0f) * u + 3.0f) * u + 1.0f) * i6; // d = 1  (t = s-1)
    w2 = ((3.0f * u - 6.0f) * u2 + 4.0f) * i6;              // d = 2  (t = s-2)
    w3 = v * v * v * i6;                                    // d = 3  (t = s-3)
}

// value of basis index t = s-d, selected branch-free (d outside [0,3] -> 0)
__device__ __forceinline__ float pick4(float w0, float w1, float w2, float w3, int d) {
    float r = 0.0f;
    r = (d == 0) ? w0 : r;
    r = (d == 1) ? w1 : r;
    r = (d == 2) ? w2 : r;
    r = (d == 3) ? w3 : r;
    return r;
}

// ---------------------------------------------------------------------------
// Main fused kernel. One block = one 64-row tile (1024 blocks, 4/CU).
// Phase 0: stage x^2 transposed into LDS (coalesced float4 reads of X).
// Phase 1: 64x128 GEMM vs S (L2-resident); 8 rows x 4 cols per thread.
// Phase 2: basis, parallelized BY OUTPUT FLOAT4 -> every global store is a
//          fully coalesced 1KB/wave float4 stream. Each lane recomputes the
//          (at most 2) features its float4 straddles via closed-form weights;
//          x is re-read from the L1/L2-hot tile as scalars.
// ---------------------------------------------------------------------------
__global__ __launch_bounds__(256, 4) void kan_main(const float* __restrict__ X,
                                                   const float* __restrict__ S,
                                                   float* __restrict__ out) {
    __shared__ __align__(16) float xsqT[DIM * LDS_STRIDE];  // [i][r], 34.8 KB

    const int tid = threadIdx.x;
    const int row0 = blockIdx.x * ROWS_PER_TILE;

    // ---------------- Phase 0: stage x^2 transposed ----------------
    const float4* X4 = (const float4*)(X + (size_t)row0 * DIM);
#pragma unroll
    for (int k = 0; k < 8; ++k) {
        int e4 = k * 256 + tid;      // float4 index in tile, 0..2047
        int e = e4 * 4;              // element index in tile
        int r = e >> 7;              // row within tile (0..63)
        int i = e & 127;             // feature (multiple of 4)
        float4 xv = X4[e4];
        xsqT[(i + 0) * LDS_STRIDE + r] = xv.x * xv.x;
        xsqT[(i + 1) * LDS_STRIDE + r] = xv.y * xv.y;
        xsqT[(i + 2) * LDS_STRIDE + r] = xv.z * xv.z;
        xsqT[(i + 3) * LDS_STRIDE + r] = xv.w * xv.w;
    }
    __syncthreads();

    // ---------------- Phase 1: interaction GEMM ----------------
    {
        const int c = tid & 31;          // col group: cols 4c..4c+3
        const int rg = tid >> 5;         // row group: rows rg*8..rg*8+7
        const int r0 = rg * 8;

        float acc[8][4];
#pragma unroll
        for (int rr = 0; rr < 8; ++rr)
#pragma unroll
            for (int q = 0; q < 4; ++q) acc[rr][q] = 0.0f;

        const float4* S4 = (const float4*)S;
#pragma unroll 4
        for (int i = 0; i < DIM; ++i) {
            float4 s = S4[i * 32 + c];                     // L2-resident, coalesced
            const float4* xr4 = (const float4*)&xsqT[i * LDS_STRIDE + r0];
            float4 xa = xr4[0];                            // broadcast b128 reads
            float4 xb = xr4[1];
            float xr[8] = {xa.x, xa.y, xa.z, xa.w, xb.x, xb.y, xb.z, xb.w};
#pragma unroll
            for (int rr = 0; rr < 8; ++rr) {
#pragma unroll
                for (int q = 0; q < 4; ++q) {
                    float sv = (q == 0) ? s.x : (q == 1) ? s.y : (q == 2) ? s.z : s.w;
                    acc[rr][q] = fmaf(xr[rr], sv, acc[rr][q]);
                }
            }
        }

#pragma unroll
        for (int rr = 0; rr < 8; ++rr) {
            float4* o = (float4*)(out + (size_t)(row0 + r0 + rr) * OUTW + DIM * NBAS + 4 * c);
            *o = make_float4(acc[rr][0], acc[rr][1], acc[rr][2], acc[rr][3]);
        }
    }

    // ---------------- Phase 2: basis, coalesced-by-output ----------------
    // Per row: 768 basis floats = 192 float4s = exactly 3 waves.
    // wave-task wt in [0,192): row = wt/3, third = wt%3; lane -> float4 j.
    // float4 j covers out floats [4j, 4j+4): feature fA = (4j)/6, and when
    // j%3==1 also feature fA+1 (the straddling case).
    {
        const int wv = tid >> 6;         // wave in block, 0..3
        const int lane = tid & 63;
#pragma unroll 2
        for (int n = 0; n < 48; ++n) {
            unsigned wt = (unsigned)(n * 4 + wv);        // 0..191
            unsigned r = wt / 3u;                        // row in tile, 0..63
            unsigned third = wt - 3u * r;                // 0..2
            unsigned j = third * 64u + (unsigned)lane;   // float4 idx in row, 0..191
            unsigned m = j % 3u;                         // straddle pattern
            unsigned o0 = 4u * j;                        // first out float
            unsigned fA = o0 / 6u;                       // 0..127
            unsigned fB = (fA < 127u) ? fA + 1u : 127u;

            const float* xrow = X + (size_t)(row0 + r) * DIM;
            float xA = xrow[fA];
            float xB = xrow[fB];

            int sA, sB;
            float a0, a1, a2, a3, b0, b1, b2, b3;
            bw(xA, sA, a0, a1, a2, a3);
            bw(xB, sB, b0, b1, b2, b3);

            // base t within feature A for slot 0:
            //   m==0 -> floats are (fA, t=0..3)
            //   m==1 -> (fA,4),(fA,5),(fB,0),(fB,1)
            //   m==2 -> (fA, t=2..5)
            int tb = (m == 0u) ? 0 : (m == 2u) ? 2 : 4;
            int dA = sA - tb;

            float r0v = pick4(a0, a1, a2, a3, dA);
            float r1v = pick4(a0, a1, a2, a3, dA - 1);
            float r2v = (m == 1u) ? pick4(b0, b1, b2, b3, sB)
                                  : pick4(a0, a1, a2, a3, dA - 2);
            float r3v = (m == 1u) ? pick4(b0, b1, b2, b3, sB - 1)
                                  : pick4(a0, a1, a2, a3, dA - 3);

            float4* o = (float4*)(out + (size_t)(row0 + r) * OUTW + o0);
            *o = make_float4(r0v, r1v, r2v, r3v);
        }
    }
}

// ---------------------------------------------------------------------------
extern "C" void kernel_launch(void* const* d_in, const int* in_sizes, int n_in,
                              void* d_out, int out_size, void* d_ws, size_t ws_size,
                              hipStream_t stream) {
    const float* X = (const float*)d_in[0];
    const float* W = (const float*)d_in[1];
    float* out = (float*)d_out;
    float* S = (float*)d_ws;   // 64 KB scratch for sigmoid(W)

    sigmoid_k<<<(DIM * DIM) / 256, 256, 0, stream>>>(W, S);
    kan_main<<<BATCH / ROWS_PER_TILE, 256, 0, stream>>>(X, S, out);
}

// Round 2
// 291.785 us; speedup vs baseline: 1.1969x; 1.0100x over previous
//
#include <hip/hip_runtime.h>
#include <math.h>

// Problem constants (fixed by the reference)
#define BATCH 65536
#define DIM 128
#define NBAS 6
#define OUTW 896              // DIM*NBAS + DIM
#define ROWS_PER_TILE 64
#define LDS_STRIDE 68         // pad: 16B-aligned b128 reads, breaks pow2 store conflicts

// ---------------------------------------------------------------------------
// Kernel 1: S = sigmoid(W), 128x128 into workspace. Trivial.
// ---------------------------------------------------------------------------
__global__ __launch_bounds__(256) void sigmoid_k(const float* __restrict__ W,
                                                 float* __restrict__ S) {
    int t = blockIdx.x * 256 + threadIdx.x;
    float w = W[t];
    S[t] = 1.0f / (1.0f + expf(-w));
}

// ---------------------------------------------------------------------------
// Closed-form uniform cubic B-spline weights (identical math to the
// Cox-de Boor ladder for knots = linspace(-1,1,10)).
// ---------------------------------------------------------------------------
__device__ __forceinline__ void bw(float x, int& s,
                                   float& w0, float& w1, float& w2, float& w3) {
    const float i6 = 0.16666666666666666f;
    float xc = fminf(fmaxf(x, -1.0f), 1.0f - 1e-6f);
    float p  = (xc + 1.0f) * 4.5f;
    float sf = floorf(p);
    float u  = p - sf;
    s = (int)sf;                       // 0..8
    float u2 = u * u;
    float v  = 1.0f - u;
    w0 = u * u2 * i6;                                       // t = s
    w1 = (((-3.0f * u + 3.0f) * u + 3.0f) * u + 1.0f) * i6; // t = s-1
    w2 = ((3.0f * u - 6.0f) * u2 + 4.0f) * i6;              // t = s-2
    w3 = v * v * v * i6;                                    // t = s-3
}

// value of basis index t = s-d, branch-free (d outside [0,3] -> 0)
__device__ __forceinline__ float pick4(float w0, float w1, float w2, float w3, int d) {
    float r = 0.0f;
    r = (d == 0) ? w0 : r;
    r = (d == 1) ? w1 : r;
    r = (d == 2) ? w2 : r;
    r = (d == 3) ? w3 : r;
    return r;
}

// ---------------------------------------------------------------------------
// Interaction GEMM: 64x128 tile vs S (L2-resident). x staged (unsquared) in
// LDS; squares computed on the fly (8 v_mul per i-iter).
// ---------------------------------------------------------------------------
__device__ __forceinline__ void do_gemm(const float* __restrict__ xT,
                                        const float* __restrict__ S,
                                        float* __restrict__ out,
                                        int row0, int tid) {
    const int c = tid & 31;          // col group: cols 4c..4c+3
    const int rg = tid >> 5;         // row group: rows rg*8..rg*8+7
    const int r0 = rg * 8;

    float acc[8][4];
#pragma unroll
    for (int rr = 0; rr < 8; ++rr)
#pragma unroll
        for (int q = 0; q < 4; ++q) acc[rr][q] = 0.0f;

    const float4* S4 = (const float4*)S;
#pragma unroll 4
    for (int i = 0; i < DIM; ++i) {
        float4 s = S4[i * 32 + c];                     // L2-resident, coalesced
        const float4* xr4 = (const float4*)&xT[i * LDS_STRIDE + r0];
        float4 xa = xr4[0];                            // broadcast b128 reads
        float4 xb = xr4[1];
        float xr[8] = {xa.x * xa.x, xa.y * xa.y, xa.z * xa.z, xa.w * xa.w,
                       xb.x * xb.x, xb.y * xb.y, xb.z * xb.z, xb.w * xb.w};
#pragma unroll
        for (int rr = 0; rr < 8; ++rr) {
#pragma unroll
            for (int q = 0; q < 4; ++q) {
                float sv = (q == 0) ? s.x : (q == 1) ? s.y : (q == 2) ? s.z : s.w;
                acc[rr][q] = fmaf(xr[rr], sv, acc[rr][q]);
            }
        }
    }

#pragma unroll
    for (int rr = 0; rr < 8; ++rr) {
        float4* o = (float4*)(out + (size_t)(row0 + r0 + rr) * OUTW + DIM * NBAS + 4 * c);
        *o = make_float4(acc[rr][0], acc[rr][1], acc[rr][2], acc[rr][3]);
    }
}

// ---------------------------------------------------------------------------
// Basis phase, coalesced-by-output. Per row: 192 float4s = 3 waves' worth.
// All per-(lane,third) indexing hoisted out of the row loop; x comes from the
// LDS tile (no global gathers). Every store is a 1KB/wave float4 stream.
// ---------------------------------------------------------------------------
__device__ __forceinline__ void do_basis(const float* __restrict__ xT,
                                         float* __restrict__ out,
                                         int row0, int tid) {
    const int lane = tid & 63;
    const int wv = tid >> 6;

    // Hoisted per-(lane,third) constants. t is compile-time after unroll, so
    // these arrays stay in registers (static indexing only).
    int offA[3], offB[3], tb[3];
    bool useB[3];
#pragma unroll
    for (int t = 0; t < 3; ++t) {
        int j = t * 64 + lane;           // float4 idx in row, 0..191
        int m = j % 3;                   // straddle pattern
        int o0 = 4 * j;                  // first out float
        int fA = o0 / 6;                 // 0..127
        int fB = (fA < 127) ? fA + 1 : 127;
        offA[t] = fA * LDS_STRIDE;
        offB[t] = fB * LDS_STRIDE;
        tb[t] = (m == 0) ? 0 : (m == 2) ? 2 : 4;
        useB[t] = (m == 1);
    }

#pragma unroll 2
    for (int rr = 0; rr < 16; ++rr) {
        int r = rr * 4 + wv;             // waves cover adjacent rows together
        float4* orow4 = (float4*)(out + (size_t)(row0 + r) * OUTW);
#pragma unroll
        for (int t = 0; t < 3; ++t) {
            float xA = xT[offA[t] + r];
            float xB = xT[offB[t] + r];
            int sA, sB;
            float a0, a1, a2, a3, b0, b1, b2, b3;
            bw(xA, sA, a0, a1, a2, a3);
            bw(xB, sB, b0, b1, b2, b3);
            int dA = sA - tb[t];
            float r0v = pick4(a0, a1, a2, a3, dA);
            float r1v = pick4(a0, a1, a2, a3, dA - 1);
            float r2v = useB[t] ? pick4(b0, b1, b2, b3, sB)
                                : pick4(a0, a1, a2, a3, dA - 2);
            float r3v = useB[t] ? pick4(b0, b1, b2, b3, sB - 1)
                                : pick4(a0, a1, a2, a3, dA - 3);
            orow4[t * 64 + lane] = make_float4(r0v, r1v, r2v, r3v);
        }
    }
}

// ---------------------------------------------------------------------------
// Main fused kernel. One block = one 64-row tile (1024 blocks, 4/CU).
// Phase 0: stage x transposed into LDS (coalesced float4 reads of X).
// Then: half the resident blocks run GEMM->basis, the other half
// basis->GEMM, so the CU overlaps the VALU-bound GEMM with the
// write-bound basis phase. Blocks b, b+256, b+512, b+768 co-reside on a CU,
// so parity comes from bit 8 of blockIdx.
// ---------------------------------------------------------------------------
__global__ __launch_bounds__(256, 4) void kan_main(const float* __restrict__ X,
                                                   const float* __restrict__ S,
                                                   float* __restrict__ out) {
    __shared__ __align__(16) float xT[DIM * LDS_STRIDE];  // [i][r], 34.8 KB

    const int tid = threadIdx.x;
    const int row0 = blockIdx.x * ROWS_PER_TILE;

    // ---------------- Phase 0: stage x transposed ----------------
    const float4* X4 = (const float4*)(X + (size_t)row0 * DIM);
#pragma unroll
    for (int k = 0; k < 8; ++k) {
        int e4 = k * 256 + tid;      // float4 index in tile, 0..2047
        int e = e4 * 4;              // element index in tile
        int r = e >> 7;              // row within tile (0..63)
        int i = e & 127;             // feature (multiple of 4)
        float4 xv = X4[e4];
        xT[(i + 0) * LDS_STRIDE + r] = xv.x;
        xT[(i + 1) * LDS_STRIDE + r] = xv.y;
        xT[(i + 2) * LDS_STRIDE + r] = xv.z;
        xT[(i + 3) * LDS_STRIDE + r] = xv.w;
    }
    __syncthreads();

    // Both phases only READ xT; either order is safe after the one barrier.
    if (((blockIdx.x >> 8) & 1) == 0) {
        do_gemm(xT, S, out, row0, tid);
        do_basis(xT, out, row0, tid);
    } else {
        do_basis(xT, out, row0, tid);
        do_gemm(xT, S, out, row0, tid);
    }
}

// ---------------------------------------------------------------------------
extern "C" void kernel_launch(void* const* d_in, const int* in_sizes, int n_in,
                              void* d_out, int out_size, void* d_ws, size_t ws_size,
                              hipStream_t stream) {
    const float* X = (const float*)d_in[0];
    const float* W = (const float*)d_in[1];
    float* out = (float*)d_out;
    float* S = (float*)d_ws;   // 64 KB scratch for sigmoid(W)

    sigmoid_k<<<(DIM * DIM) / 256, 256, 0, stream>>>(W, S);
    kan_main<<<BATCH / ROWS_PER_TILE, 256, 0, stream>>>(X, S, out);
}

// Round 3
// 290.543 us; speedup vs baseline: 1.2020x; 1.0043x over previous
//
#include <hip/hip_runtime.h>
#include <math.h>

// Problem constants (fixed by the reference)
#define BATCH 65536
#define DIM 128
#define NBAS 6
#define OUTW 896              // DIM*NBAS + DIM
#define ROWS_PER_TILE 32
#define LDS_F4 33             // float4 stride per LDS row (32 + 1 pad)
#define LDS_F 132             // float stride per LDS row

typedef float f4v __attribute__((ext_vector_type(4)));

// ---------------------------------------------------------------------------
// Kernel 1: S = sigmoid(W), 128x128 into workspace. Trivial.
// ---------------------------------------------------------------------------
__global__ __launch_bounds__(256) void sigmoid_k(const float* __restrict__ W,
                                                 float* __restrict__ S) {
    int t = blockIdx.x * 256 + threadIdx.x;
    float w = W[t];
    S[t] = 1.0f / (1.0f + expf(-w));
}

// ---------------------------------------------------------------------------
// Closed-form uniform cubic B-spline weights (identical math to the
// Cox-de Boor ladder for knots = linspace(-1,1,10)).
// ---------------------------------------------------------------------------
__device__ __forceinline__ void bw(float x, int& s,
                                   float& w0, float& w1, float& w2, float& w3) {
    const float i6 = 0.16666666666666666f;
    float xc = fminf(fmaxf(x, -1.0f), 1.0f - 1e-6f);
    float p  = (xc + 1.0f) * 4.5f;
    float sf = floorf(p);
    float u  = p - sf;
    s = (int)sf;                       // 0..8
    float u2 = u * u;
    float v  = 1.0f - u;
    w0 = u * u2 * i6;                                       // t = s
    w1 = (((-3.0f * u + 3.0f) * u + 3.0f) * u + 1.0f) * i6; // t = s-1
    w2 = ((3.0f * u - 6.0f) * u2 + 4.0f) * i6;              // t = s-2
    w3 = v * v * v * i6;                                    // t = s-3
}

// value of basis index t = s-d, branch-free (d outside [0,3] -> 0)
__device__ __forceinline__ float pick4(float w0, float w1, float w2, float w3, int d) {
    float r = 0.0f;
    r = (d == 0) ? w0 : r;
    r = (d == 1) ? w1 : r;
    r = (d == 2) ? w2 : r;
    r = (d == 3) ? w3 : r;
    return r;
}

// ---------------------------------------------------------------------------
// Main fused kernel. 32-row tiles -> 2048 blocks, 16.9 KB LDS, 8 blocks/CU
// (32 waves/CU — double the previous occupancy; that is the point of this
// version). LDS tile is ROW-major [32][132]: float4 copy-in is conflict-free,
// GEMM reads are half-wave broadcasts, basis reads are <=2-way.
// All out stores are nontemporal (out is write-once, never re-read) so the
// 235 MB write stream stops evicting S / X from L2.
// ---------------------------------------------------------------------------
__global__ __launch_bounds__(256, 8) void kan_main(const float* __restrict__ X,
                                                   const float* __restrict__ S,
                                                   float* __restrict__ out) {
    __shared__ __align__(16) float xTf[ROWS_PER_TILE * LDS_F];  // 16.9 KB

    const int tid = threadIdx.x;
    const int row0 = blockIdx.x * ROWS_PER_TILE;

    // ---------------- Phase 0: stage x row-major (straight copy) ----------
    const float4* X4 = (const float4*)(X + (size_t)row0 * DIM);
    float4* xT4 = (float4*)xTf;
#pragma unroll
    for (int k = 0; k < 4; ++k) {
        int e4 = k * 256 + tid;      // float4 index in tile, 0..1023
        int r = e4 >> 5;             // row within tile (0..31)
        int i4 = e4 & 31;            // float4 within row
        xT4[r * LDS_F4 + i4] = X4[e4];
    }
    __syncthreads();

    // ---------------- Phase 1: interaction GEMM ----------------
    {
        const int c = tid & 31;          // col group: cols 4c..4c+3
        const int r0 = (tid >> 5) * 4;   // rows r0..r0+3

        float acc[4][4];
#pragma unroll
        for (int rr = 0; rr < 4; ++rr)
#pragma unroll
            for (int q = 0; q < 4; ++q) acc[rr][q] = 0.0f;

        const float4* S4 = (const float4*)S;
        const float* xp0 = xTf + (r0 + 0) * LDS_F;
        const float* xp1 = xTf + (r0 + 1) * LDS_F;
        const float* xp2 = xTf + (r0 + 2) * LDS_F;
        const float* xp3 = xTf + (r0 + 3) * LDS_F;
#pragma unroll 2
        for (int i = 0; i < DIM; ++i) {
            float4 s = S4[i * 32 + c];       // L2-resident, coalesced
            float x0 = xp0[i], x1 = xp1[i], x2 = xp2[i], x3 = xp3[i];  // broadcasts
            float xq[4] = {x0 * x0, x1 * x1, x2 * x2, x3 * x3};
#pragma unroll
            for (int rr = 0; rr < 4; ++rr) {
#pragma unroll
                for (int q = 0; q < 4; ++q) {
                    float sv = (q == 0) ? s.x : (q == 1) ? s.y : (q == 2) ? s.z : s.w;
                    acc[rr][q] = fmaf(xq[rr], sv, acc[rr][q]);
                }
            }
        }

#pragma unroll
        for (int rr = 0; rr < 4; ++rr) {
            f4v v = {acc[rr][0], acc[rr][1], acc[rr][2], acc[rr][3]};
            __builtin_nontemporal_store(
                v, (f4v*)(out + (size_t)(row0 + r0 + rr) * OUTW + DIM * NBAS + 4 * c));
        }
    }

    // ---------------- Phase 2: basis, coalesced-by-output ----------------
    // Per row: 192 float4s = 3 waves' worth; per-(lane,third) indexing hoisted.
    {
        const int lane = tid & 63;
        const int wv = tid >> 6;

        int fAh[3], fBh[3], tbh[3];
        bool uBh[3];
#pragma unroll
        for (int t = 0; t < 3; ++t) {
            int j = t * 64 + lane;           // float4 idx in row, 0..191
            int m = j % 3;                   // straddle pattern
            int o0 = 4 * j;                  // first out float
            int fA = o0 / 6;                 // 0..127
            fAh[t] = fA;
            fBh[t] = (fA < 127) ? fA + 1 : 127;
            tbh[t] = (m == 0) ? 0 : (m == 2) ? 2 : 4;
            uBh[t] = (m == 1);
        }

#pragma unroll 2
        for (int rr = 0; rr < 8; ++rr) {
            int r = rr * 4 + wv;             // waves cover adjacent rows together
            const float* xrow = xTf + r * LDS_F;
            float* orow = out + (size_t)(row0 + r) * OUTW;
#pragma unroll
            for (int t = 0; t < 3; ++t) {
                float xA = xrow[fAh[t]];
                float xB = xrow[fBh[t]];
                int sA, sB;
                float a0, a1, a2, a3, b0, b1, b2, b3;
                bw(xA, sA, a0, a1, a2, a3);
                bw(xB, sB, b0, b1, b2, b3);
                int dA = sA - tbh[t];
                float r0v = pick4(a0, a1, a2, a3, dA);
                float r1v = pick4(a0, a1, a2, a3, dA - 1);
                float r2v = uBh[t] ? pick4(b0, b1, b2, b3, sB)
                                   : pick4(a0, a1, a2, a3, dA - 2);
                float r3v = uBh[t] ? pick4(b0, b1, b2, b3, sB - 1)
                                   : pick4(a0, a1, a2, a3, dA - 3);
                f4v v = {r0v, r1v, r2v, r3v};
                __builtin_nontemporal_store(v, (f4v*)(orow + 4 * (t * 64 + lane)));
            }
        }
    }
}

// ---------------------------------------------------------------------------
extern "C" void kernel_launch(void* const* d_in, const int* in_sizes, int n_in,
                              void* d_out, int out_size, void* d_ws, size_t ws_size,
                              hipStream_t stream) {
    const float* X = (const float*)d_in[0];
    const float* W = (const float*)d_in[1];
    float* out = (float*)d_out;
    float* S = (float*)d_ws;   // 64 KB scratch for sigmoid(W)

    sigmoid_k<<<(DIM * DIM) / 256, 256, 0, stream>>>(W, S);
    kan_main<<<BATCH / ROWS_PER_TILE, 256, 0, stream>>>(X, S, out);
}